// Round 7
// baseline (35.692 us; speedup 1.0000x reference)
//
#include <hip/hip_runtime.h>

#define DIM 32
#define H1 64
#define BLK 256
#define SPB 64           // samples per block: 4 threads cooperate per sample
#define RS 104           // LDS row stride in bf16 elems (208 B, 16B-aligned)

typedef __attribute__((ext_vector_type(8))) short bf16x8;
typedef __attribute__((ext_vector_type(4))) float f32x4;

__device__ __forceinline__ unsigned short f2bf(float f) {
    unsigned u = __float_as_uint(f);
    unsigned r = ((u >> 16) & 1u) + 0x7fffu;   // round-to-nearest-even
    return (unsigned short)((u + r) >> 16);
}

__global__ __launch_bounds__(BLK, 6) void mtn_fused(
    const int* __restrict__ uid, const int* __restrict__ iid,
    const float* __restrict__ Uw, const float* __restrict__ Qw,
    const float* __restrict__ Aw, const float* __restrict__ Bw,
    const float* __restrict__ W1, const float* __restrict__ b1g,
    const float* __restrict__ W2, const float* __restrict__ b2g,
    float* __restrict__ out, int batch)
{
    __shared__ unsigned short Xs[SPB][RS];   // 13.3 KB

    const int t    = threadIdx.x;
    const int srow = t >> 2;       // local sample row (0..63)
    const int h    = t & 3;        // quarter of the embedding this thread owns
    const int s    = blockIdx.x * SPB + srow;
    const bool valid = (s < batch);

    const int u_idx = valid ? uid[s] : 0;
    const int q_idx = valid ? iid[s] : 0;

    // quarter-row gathers: 2 float4 of u, 2 float4 of q per thread (32 B each)
    const float4* up = (const float4*)(Uw + (long long)u_idx * DIM + h * 8);
    const float4* qp = (const float4*)(Qw + (long long)q_idx * DIM + h * 8);
    float4 uv0 = up[0], uv1 = up[1];
    float4 qv0 = qp[0], qv1 = qp[1];
    // lanes h=0/1 fetch the scalar biases; h=2/3 contribute 0
    float bias = 0.f;
    if (h == 0) bias = Aw[u_idx];
    else if (h == 1) bias = Bw[q_idx];

    // ---- products, partial dot, stage x = [u|q|uq] quarters as bf16 ----
    float dotp = bias;
    {
        bf16x8 ubv, qbv, pbv;
        const float ue[8] = {uv0.x,uv0.y,uv0.z,uv0.w, uv1.x,uv1.y,uv1.z,uv1.w};
        const float qe[8] = {qv0.x,qv0.y,qv0.z,qv0.w, qv1.x,qv1.y,qv1.z,qv1.w};
#pragma unroll
        for (int e = 0; e < 8; ++e) {
            float pp = ue[e] * qe[e];
            dotp += pp;
            ubv[e] = (short)f2bf(ue[e]);
            qbv[e] = (short)f2bf(qe[e]);
            pbv[e] = (short)f2bf(pp);
        }
        *(bf16x8*)&Xs[srow][h * 8]      = ubv;
        *(bf16x8*)&Xs[srow][32 + h * 8] = qbv;
        *(bf16x8*)&Xs[srow][64 + h * 8] = pbv;
    }
    // 4-lane group holds the four quarters + (Aw, Bw) in lanes 0,1
    dotp += __shfl_xor(dotp, 1);
    dotp += __shfl_xor(dotp, 2);
    if (valid && h == 0) out[s] = dotp;

    __syncthreads();

    // ---- phase 2: MFMA MLP (phase-1 registers are dead past the barrier) ----
    const int lane = t & 63;
    const int wave = t >> 6;
    const int lr = lane & 15;      // B/C column
    const int lg = lane >> 4;      // k-group / C row-group

    // W1 B-fragments built per-lane from global W1 (24 KB, L1-hot):
    // bfrag[ks][n][e] = bf16( W1[n*16+lr][ks*32 + lg*8 + e] )
    bf16x8 bfrag[3][4];
#pragma unroll
    for (int ks = 0; ks < 3; ++ks)
#pragma unroll
        for (int n = 0; n < 4; ++n) {
            const float4* wp = (const float4*)(W1 + (n * 16 + lr) * 96 + ks * 32 + lg * 8);
            float4 w0 = wp[0], w1 = wp[1];
            bf16x8 f;
            f[0] = (short)f2bf(w0.x); f[1] = (short)f2bf(w0.y);
            f[2] = (short)f2bf(w0.z); f[3] = (short)f2bf(w0.w);
            f[4] = (short)f2bf(w1.x); f[5] = (short)f2bf(w1.y);
            f[6] = (short)f2bf(w1.z); f[7] = (short)f2bf(w1.w);
            bfrag[ks][n] = f;
        }
    float w2l[4], b1l[4];
#pragma unroll
    for (int n = 0; n < 4; ++n) {
        w2l[n] = W2[n * 16 + lr];
        b1l[n] = b1g[n * 16 + lr];
    }
    const float b2v = b2g[0];

    // one 16-sample m-tile per wave
    const int rowb = wave * 16 + lr;
    bf16x8 a0 = *(const bf16x8*)&Xs[rowb][0 * 32 + lg * 8];
    bf16x8 a1 = *(const bf16x8*)&Xs[rowb][1 * 32 + lg * 8];
    bf16x8 a2 = *(const bf16x8*)&Xs[rowb][2 * 32 + lg * 8];

    f32x4 c0 = {b1l[0], b1l[0], b1l[0], b1l[0]};
    f32x4 c1 = {b1l[1], b1l[1], b1l[1], b1l[1]};
    f32x4 c2 = {b1l[2], b1l[2], b1l[2], b1l[2]};
    f32x4 c3 = {b1l[3], b1l[3], b1l[3], b1l[3]};

    c0 = __builtin_amdgcn_mfma_f32_16x16x32_bf16(a0, bfrag[0][0], c0, 0, 0, 0);
    c1 = __builtin_amdgcn_mfma_f32_16x16x32_bf16(a0, bfrag[0][1], c1, 0, 0, 0);
    c2 = __builtin_amdgcn_mfma_f32_16x16x32_bf16(a0, bfrag[0][2], c2, 0, 0, 0);
    c3 = __builtin_amdgcn_mfma_f32_16x16x32_bf16(a0, bfrag[0][3], c3, 0, 0, 0);
    c0 = __builtin_amdgcn_mfma_f32_16x16x32_bf16(a1, bfrag[1][0], c0, 0, 0, 0);
    c1 = __builtin_amdgcn_mfma_f32_16x16x32_bf16(a1, bfrag[1][1], c1, 0, 0, 0);
    c2 = __builtin_amdgcn_mfma_f32_16x16x32_bf16(a1, bfrag[1][2], c2, 0, 0, 0);
    c3 = __builtin_amdgcn_mfma_f32_16x16x32_bf16(a1, bfrag[1][3], c3, 0, 0, 0);
    c0 = __builtin_amdgcn_mfma_f32_16x16x32_bf16(a2, bfrag[2][0], c0, 0, 0, 0);
    c1 = __builtin_amdgcn_mfma_f32_16x16x32_bf16(a2, bfrag[2][1], c1, 0, 0, 0);
    c2 = __builtin_amdgcn_mfma_f32_16x16x32_bf16(a2, bfrag[2][2], c2, 0, 0, 0);
    c3 = __builtin_amdgcn_mfma_f32_16x16x32_bf16(a2, bfrag[2][3], c3, 0, 0, 0);

    // layer 2: score = relu( sum_j relu(h_j)*W2[j] + b2 )
    float tot[4];
#pragma unroll
    for (int r = 0; r < 4; ++r) {
        float p = fmaxf(c0[r], 0.f) * w2l[0] + fmaxf(c1[r], 0.f) * w2l[1]
                + fmaxf(c2[r], 0.f) * w2l[2] + fmaxf(c3[r], 0.f) * w2l[3];
        p += __shfl_xor(p, 1);
        p += __shfl_xor(p, 2);
        p += __shfl_xor(p, 4);
        p += __shfl_xor(p, 8);
        tot[r] = p;
    }
    if (lr < 4) {
        int so = blockIdx.x * SPB + wave * 16 + lg * 4 + lr;
        if (so < batch) out[batch + so] = fmaxf(tot[lr] + b2v, 0.f);
    }
}

extern "C" void kernel_launch(void* const* d_in, const int* in_sizes, int n_in,
                              void* d_out, int out_size, void* d_ws, size_t ws_size,
                              hipStream_t stream) {
    const int*   uid = (const int*)  d_in[0];
    const int*   iid = (const int*)  d_in[1];
    const float* Uw  = (const float*)d_in[2];
    const float* Qw  = (const float*)d_in[3];
    const float* Aw  = (const float*)d_in[4];
    const float* Bw  = (const float*)d_in[5];
    const float* W1  = (const float*)d_in[6];
    const float* b1  = (const float*)d_in[7];
    const float* W2  = (const float*)d_in[8];
    const float* b2  = (const float*)d_in[9];
    float* out = (float*)d_out;
    int batch = in_sizes[0];

    int blocks = (batch + SPB - 1) / SPB;
    hipLaunchKernelGGL(mtn_fused, dim3(blocks), dim3(BLK), 0, stream,
                       uid, iid, Uw, Qw, Aw, Bw, W1, b1, W2, b2, out, batch);
}

// Round 8
// 18.151 us; speedup vs baseline: 1.9664x; 1.9664x over previous
//
#include <hip/hip_runtime.h>

#define DIM 32
#define H1 64
#define BLK 256
#define SPB 128          // samples per block: 2 threads cooperate per sample
#define RS 104           // LDS row stride in bf16 elems (208 B, 16B-aligned)

typedef __attribute__((ext_vector_type(8))) short bf16x8;
typedef __attribute__((ext_vector_type(4))) float f32x4;

__device__ __forceinline__ unsigned short f2bf(float f) {
    unsigned u = __float_as_uint(f);
    unsigned r = ((u >> 16) & 1u) + 0x7fffu;   // round-to-nearest-even
    return (unsigned short)((u + r) >> 16);
}

__global__ __launch_bounds__(BLK, 4) void mtn_fused(
    const int* __restrict__ uid, const int* __restrict__ iid,
    const float* __restrict__ Uw, const float* __restrict__ Qw,
    const float* __restrict__ Aw, const float* __restrict__ Bw,
    const float* __restrict__ W1, const float* __restrict__ b1g,
    const float* __restrict__ W2, const float* __restrict__ b2g,
    float* __restrict__ out, int batch)
{
    __shared__ unsigned short Xs[SPB][RS];            // 26.6 KB
    __shared__ __align__(16) unsigned short Bp[3 * 4 * 64 * 8];  // 12.3 KB, MFMA B-frag order

    const int t    = threadIdx.x;
    const int srow = t >> 1;       // local sample row
    const int h    = t & 1;        // which half of the embedding this thread owns
    const int s    = blockIdx.x * SPB + srow;
    const bool valid = (s < batch);

    const int u_idx = valid ? uid[s] : 0;
    const int q_idx = valid ? iid[s] : 0;

    // half-row gathers: 4 float4 of u, 4 float4 of q per thread (64 B each).
    // Issued first so their latency overlaps the W1 staging below.
    const float4* up = (const float4*)(Uw + (long long)u_idx * DIM + h * 16);
    const float4* qp = (const float4*)(Qw + (long long)q_idx * DIM + h * 16);
    float4 uv0 = up[0], uv1 = up[1], uv2 = up[2], uv3 = up[3];
    float4 qv0 = qp[0], qv1 = qp[1], qv2 = qp[2], qv3 = qp[3];
    const float* bptr = h ? (Bw + q_idx) : (Aw + u_idx);
    float bias = *bptr;

    // ---- cooperative W1 -> Bpack(bf16) staging into LDS (once per block) ----
    // Bp[(((ks*4+n)*64)+l)*8+e] = bf16(W1[n*16+(l&15)][ks*32+((l>>4)<<3)+e])
    // Inverse map from linear W1 index (j*96+k):
    //   n=j>>4, lr=j&15, ks=k>>5, lg=(k>>3)&3, e=k&7, l=lg*16+lr
    {
        const float4* w4 = (const float4*)W1;
#pragma unroll
        for (int it = 0; it < 6; ++it) {
            int base4 = t + it * BLK;            // float4 index, 0..1535
            float4 w = w4[base4];
            int lin = base4 * 4;
            float we[4] = {w.x, w.y, w.z, w.w};
#pragma unroll
            for (int e4 = 0; e4 < 4; ++e4) {
                int lidx = lin + e4;
                int j = lidx / 96;
                int k = lidx - j * 96;
                int n  = j >> 4, lr = j & 15;
                int ks = k >> 5, lg = (k >> 3) & 3, e = k & 7;
                int l  = lg * 16 + lr;
                Bp[(((ks * 4 + n) << 6) + l) * 8 + e] = f2bf(we[e4]);
            }
        }
    }

    // ---- products, partial dot, stage x = [u|q|uq] halves as bf16 ----
    float dotp = bias;
    {
        bf16x8 ubv[2], qbv[2], pbv[2];
        const float ue[16] = {uv0.x,uv0.y,uv0.z,uv0.w, uv1.x,uv1.y,uv1.z,uv1.w,
                              uv2.x,uv2.y,uv2.z,uv2.w, uv3.x,uv3.y,uv3.z,uv3.w};
        const float qe[16] = {qv0.x,qv0.y,qv0.z,qv0.w, qv1.x,qv1.y,qv1.z,qv1.w,
                              qv2.x,qv2.y,qv2.z,qv2.w, qv3.x,qv3.y,qv3.z,qv3.w};
#pragma unroll
        for (int e = 0; e < 16; ++e) {
            float pp = ue[e] * qe[e];
            dotp += pp;
            ubv[e >> 3][e & 7] = (short)f2bf(ue[e]);
            qbv[e >> 3][e & 7] = (short)f2bf(qe[e]);
            pbv[e >> 3][e & 7] = (short)f2bf(pp);
        }
        *(bf16x8*)&Xs[srow][h * 16]          = ubv[0];
        *(bf16x8*)&Xs[srow][h * 16 + 8]      = ubv[1];
        *(bf16x8*)&Xs[srow][32 + h * 16]     = qbv[0];
        *(bf16x8*)&Xs[srow][32 + h * 16 + 8] = qbv[1];
        *(bf16x8*)&Xs[srow][64 + h * 16]     = pbv[0];
        *(bf16x8*)&Xs[srow][64 + h * 16 + 8] = pbv[1];
    }
    dotp += __shfl_xor(dotp, 1);
    if (valid && h == 0) out[s] = dotp;

    __syncthreads();

    // ---- phase 2: MFMA MLP ----
    const int lane = t & 63;
    const int wave = t >> 6;
    const int lr = lane & 15;      // B/C column
    const int lg = lane >> 4;      // k-group / C row-group

    // W1 B-fragments from LDS (12 x ds_read_b128, conflict-free: lane-contig)
    bf16x8 bfrag[3][4];
    {
        const bf16x8* bp = (const bf16x8*)Bp;
#pragma unroll
        for (int ks = 0; ks < 3; ++ks)
#pragma unroll
            for (int n = 0; n < 4; ++n)
                bfrag[ks][n] = bp[(ks * 4 + n) * 64 + lane];
    }
    float w2l[4], b1l[4];
#pragma unroll
    for (int n = 0; n < 4; ++n) {
        w2l[n] = W2[n * 16 + lr];
        b1l[n] = b1g[n * 16 + lr];
    }
    const float b2v = b2g[0];

    const int sbase = blockIdx.x * SPB;
#pragma unroll 1
    for (int mm = 0; mm < 2; ++mm) {
        const int rowb = wave * 32 + mm * 16 + lr;
        bf16x8 a0 = *(const bf16x8*)&Xs[rowb][0 * 32 + lg * 8];
        bf16x8 a1 = *(const bf16x8*)&Xs[rowb][1 * 32 + lg * 8];
        bf16x8 a2 = *(const bf16x8*)&Xs[rowb][2 * 32 + lg * 8];

        f32x4 c0 = {b1l[0], b1l[0], b1l[0], b1l[0]};
        f32x4 c1 = {b1l[1], b1l[1], b1l[1], b1l[1]};
        f32x4 c2 = {b1l[2], b1l[2], b1l[2], b1l[2]};
        f32x4 c3 = {b1l[3], b1l[3], b1l[3], b1l[3]};

        c0 = __builtin_amdgcn_mfma_f32_16x16x32_bf16(a0, bfrag[0][0], c0, 0, 0, 0);
        c1 = __builtin_amdgcn_mfma_f32_16x16x32_bf16(a0, bfrag[0][1], c1, 0, 0, 0);
        c2 = __builtin_amdgcn_mfma_f32_16x16x32_bf16(a0, bfrag[0][2], c2, 0, 0, 0);
        c3 = __builtin_amdgcn_mfma_f32_16x16x32_bf16(a0, bfrag[0][3], c3, 0, 0, 0);
        c0 = __builtin_amdgcn_mfma_f32_16x16x32_bf16(a1, bfrag[1][0], c0, 0, 0, 0);
        c1 = __builtin_amdgcn_mfma_f32_16x16x32_bf16(a1, bfrag[1][1], c1, 0, 0, 0);
        c2 = __builtin_amdgcn_mfma_f32_16x16x32_bf16(a1, bfrag[1][2], c2, 0, 0, 0);
        c3 = __builtin_amdgcn_mfma_f32_16x16x32_bf16(a1, bfrag[1][3], c3, 0, 0, 0);
        c0 = __builtin_amdgcn_mfma_f32_16x16x32_bf16(a2, bfrag[2][0], c0, 0, 0, 0);
        c1 = __builtin_amdgcn_mfma_f32_16x16x32_bf16(a2, bfrag[2][1], c1, 0, 0, 0);
        c2 = __builtin_amdgcn_mfma_f32_16x16x32_bf16(a2, bfrag[2][2], c2, 0, 0, 0);
        c3 = __builtin_amdgcn_mfma_f32_16x16x32_bf16(a2, bfrag[2][3], c3, 0, 0, 0);

        // layer 2: score = relu( sum_j relu(h_j)*W2[j] + b2 )
        float tot[4];
#pragma unroll
        for (int r = 0; r < 4; ++r) {
            float p = fmaxf(c0[r], 0.f) * w2l[0] + fmaxf(c1[r], 0.f) * w2l[1]
                    + fmaxf(c2[r], 0.f) * w2l[2] + fmaxf(c3[r], 0.f) * w2l[3];
            p += __shfl_xor(p, 1);
            p += __shfl_xor(p, 2);
            p += __shfl_xor(p, 4);
            p += __shfl_xor(p, 8);
            tot[r] = p;
        }
        if (lr < 4) {
            int so = sbase + wave * 32 + mm * 16 + lg * 4 + lr;
            if (so < batch) out[batch + so] = fmaxf(tot[lr] + b2v, 0.f);
        }
    }
}

extern "C" void kernel_launch(void* const* d_in, const int* in_sizes, int n_in,
                              void* d_out, int out_size, void* d_ws, size_t ws_size,
                              hipStream_t stream) {
    const int*   uid = (const int*)  d_in[0];
    const int*   iid = (const int*)  d_in[1];
    const float* Uw  = (const float*)d_in[2];
    const float* Qw  = (const float*)d_in[3];
    const float* Aw  = (const float*)d_in[4];
    const float* Bw  = (const float*)d_in[5];
    const float* W1  = (const float*)d_in[6];
    const float* b1  = (const float*)d_in[7];
    const float* W2  = (const float*)d_in[8];
    const float* b2  = (const float*)d_in[9];
    float* out = (float*)d_out;
    int batch = in_sizes[0];

    int blocks = (batch + SPB - 1) / SPB;
    hipLaunchKernelGGL(mtn_fused, dim3(blocks), dim3(BLK), 0, stream,
                       uid, iid, Uw, Qw, Aw, Bw, W1, b1, W2, b2, out, batch);
}